// Round 1
// baseline (2319.568 us; speedup 1.0000x reference)
//
#include <hip/hip_runtime.h>

#define THREADS 256

__global__ void k_zero_cnt(unsigned* __restrict__ cnt, int n){
  int i = blockIdx.x*blockDim.x + threadIdx.x;
  if(i < n) cnt[i] = 0u;
}

__global__ void k_count(const int* __restrict__ dst, unsigned* __restrict__ cnt, int E){
  int e = blockIdx.x*blockDim.x + threadIdx.x;
  if(e < E) atomicAdd(&cnt[dst[e]], 1u);
}

__global__ void k_dinv(const unsigned* __restrict__ cnt, float* __restrict__ dinv, int n){
  int i = blockIdx.x*blockDim.x + threadIdx.x;
  if(i < n) dinv[i] = rsqrtf((float)(cnt[i] + 1u));  // +1 self-loop
}

// C[M,NC] = A[M,K] @ W[K,NC], optional relu on A load. M must divide RPB.
template<int K, int NC, bool RELU>
__global__ void k_gemm(const float* __restrict__ A, const float* __restrict__ W,
                       float* __restrict__ H, int M){
  constexpr int LPR = NC/4;          // lanes per row
  constexpr int RPB = THREADS/LPR;   // rows per block
  __shared__ float As[RPB*K];
  const int row0 = blockIdx.x * RPB;
  const float4* A4 = (const float4*)(A + (size_t)row0*K);
  float4* As4 = (float4*)As;
  #pragma unroll
  for(int i = threadIdx.x; i < RPB*K/4; i += THREADS){
    float4 v = A4[i];
    if(RELU){
      v.x=fmaxf(v.x,0.f); v.y=fmaxf(v.y,0.f);
      v.z=fmaxf(v.z,0.f); v.w=fmaxf(v.w,0.f);
    }
    As4[i] = v;
  }
  __syncthreads();
  const int r  = threadIdx.x / LPR;
  const int cg = threadIdx.x % LPR;
  const float* a = As + r*K;
  const float4* W4 = (const float4*)W;
  float4 acc = make_float4(0.f,0.f,0.f,0.f);
  #pragma unroll 8
  for(int k=0;k<K;k++){
    float av = a[k];
    float4 w = W4[k*LPR + cg];
    acc.x = fmaf(av, w.x, acc.x);
    acc.y = fmaf(av, w.y, acc.y);
    acc.z = fmaf(av, w.z, acc.z);
    acc.w = fmaf(av, w.w, acc.w);
  }
  ((float4*)H)[(size_t)(row0 + r)*LPR + cg] = acc;
}

// out[i,:] = h[i,:]*dinv[i]^2 + b   (self-loop message + bias)
template<int NC>
__global__ void k_init_out(const float* __restrict__ h, const float* __restrict__ dinv,
                           const float* __restrict__ b, float* __restrict__ out, int M){
  int i = blockIdx.x*blockDim.x + threadIdx.x;   // over M*NC/4
  if(i >= M*(NC/4)) return;
  int row = i/(NC/4), cg = i%(NC/4);
  float dv = dinv[row]; float nrm = dv*dv;
  float4 v = ((const float4*)h)[i];
  float4 bb = ((const float4*)b)[cg];
  float4 o;
  o.x = fmaf(v.x, nrm, bb.x); o.y = fmaf(v.y, nrm, bb.y);
  o.z = fmaf(v.z, nrm, bb.z); o.w = fmaf(v.w, nrm, bb.w);
  ((float4*)out)[i] = o;
}

// out[dst,:] += h[src,:] * dinv[src]*dinv[dst], LPE lanes x float4 per edge
template<int LPE>
__global__ void k_scatter(const int* __restrict__ ei, const float* __restrict__ dinv,
                          const float* __restrict__ h, float* __restrict__ out, int E){
  long long idx = (long long)blockIdx.x*THREADS + threadIdx.x;
  int e    = (int)(idx / LPE);
  int lane = (int)(idx % LPE);
  if(e >= E) return;
  int s = ei[e], d = ei[E+e];
  float nrm = dinv[s]*dinv[d];
  float4 v = ((const float4*)h)[(size_t)s*LPE + lane];
  float* o = out + (size_t)d*(4*LPE) + (size_t)lane*4;
  unsafeAtomicAdd(o+0, v.x*nrm);
  unsafeAtomicAdd(o+1, v.y*nrm);
  unsafeAtomicAdd(o+2, v.z*nrm);
  unsafeAtomicAdd(o+3, v.w*nrm);
}

extern "C" void kernel_launch(void* const* d_in, const int* in_sizes, int n_in,
                              void* d_out, int out_size, void* d_ws, size_t ws_size,
                              hipStream_t stream){
  const float* feat = (const float*)d_in[0];
  const int*   ei   = (const int*)d_in[1];
  const float* W1   = (const float*)d_in[2];
  const float* b1   = (const float*)d_in[3];
  const float* W2   = (const float*)d_in[4];
  const float* b2   = (const float*)d_in[5];
  float* out = (float*)d_out;

  const int M = in_sizes[0] / 256;   // 50000 nodes
  const int E = in_sizes[1] / 2;     // 800000 edges

  float* ws   = (float*)d_ws;
  unsigned* cnt = (unsigned*)ws;               // M ints
  float* dinv = ws + 50176;                    // M floats
  float* h1   = ws + 100352;                   // M*128
  float* out1 = h1 + (size_t)M*128;            // M*128
  float* h2   = h1;                            // reuse (h1 dead after scatter1)

  const int nbN = (M + THREADS-1)/THREADS;
  k_zero_cnt<<<nbN, THREADS, 0, stream>>>(cnt, M);
  k_count<<<(E+THREADS-1)/THREADS, THREADS, 0, stream>>>(ei + E, cnt, E);
  k_dinv<<<nbN, THREADS, 0, stream>>>(cnt, dinv, M);

  // ----- layer 1: 256 -> 128 -----
  k_gemm<256,128,false><<<M/8, THREADS, 0, stream>>>(feat, W1, h1, M);
  k_init_out<128><<<(M*32 + THREADS-1)/THREADS, THREADS, 0, stream>>>(h1, dinv, b1, out1, M);
  {
    long long tot = (long long)E*32;
    k_scatter<32><<<(int)((tot+THREADS-1)/THREADS), THREADS, 0, stream>>>(ei, dinv, h1, out1, E);
  }

  // ----- layer 2: 128 -> 64 (relu fused into A load) -----
  k_gemm<128,64,true><<<M/16, THREADS, 0, stream>>>(out1, W2, h2, M);
  k_init_out<64><<<(M*16 + THREADS-1)/THREADS, THREADS, 0, stream>>>(h2, dinv, b2, out, M);
  {
    long long tot = (long long)E*16;
    k_scatter<16><<<(int)((tot+THREADS-1)/THREADS), THREADS, 0, stream>>>(ei, dinv, h2, out, E);
  }
}

// Round 2
// 538.766 us; speedup vs baseline: 4.3053x; 4.3053x over previous
//
#include <hip/hip_runtime.h>

#define THREADS 256

__global__ void k_zero_cnt(unsigned* __restrict__ cnt, int n){
  int i = blockIdx.x*blockDim.x + threadIdx.x;
  if(i < n) cnt[i] = 0u;
}

__global__ void k_count(const int* __restrict__ dst, unsigned* __restrict__ cnt, int E){
  int e = blockIdx.x*blockDim.x + threadIdx.x;
  if(e < E) atomicAdd(&cnt[dst[e]], 1u);
}

// single-block exclusive scan over cnt[0..M) -> off[0..M], off[M]=E
__global__ void k_scan(const unsigned* __restrict__ cnt, int* __restrict__ off, int M){
  __shared__ int part[1024];
  const int t = threadIdx.x;
  const int C = (M + 1023)/1024;
  const int base = t*C;
  int s = 0;
  for(int i=0;i<C;i++){ int idx=base+i; if(idx<M) s += (int)cnt[idx]; }
  part[t] = s;
  __syncthreads();
  for(int ofs=1; ofs<1024; ofs<<=1){
    int v = (t>=ofs)? part[t-ofs] : 0;
    __syncthreads();
    part[t] += v;
    __syncthreads();
  }
  int run = (t==0)? 0 : part[t-1];
  for(int i=0;i<C;i++){
    int idx=base+i;
    if(idx<M){ off[idx]=run; run += (int)cnt[idx]; }
  }
  if(t==1023) off[M] = part[1023];
}

__global__ void k_node_init(const unsigned* __restrict__ cnt, const int* __restrict__ off,
                            float* __restrict__ dinv, int* __restrict__ cursor, int M){
  int i = blockIdx.x*blockDim.x + threadIdx.x;
  if(i < M){
    dinv[i] = rsqrtf((float)(cnt[i] + 1u));  // +1 self-loop
    cursor[i] = off[i];
  }
}

__global__ void k_build(const int* __restrict__ ei, int* __restrict__ cursor,
                        int* __restrict__ ssrc, int E){
  int e = blockIdx.x*blockDim.x + threadIdx.x;
  if(e < E){
    int s = ei[e], d = ei[E+e];
    int p = atomicAdd(&cursor[d], 1);
    ssrc[p] = s;
  }
}

// H[M,NC] = (relu?)(A[M,K]) @ W[K,NC], optionally scaled per-row by dinv[row]
template<int K, int NC, bool RELU, bool SCALE>
__global__ void k_gemm(const float* __restrict__ A, const float* __restrict__ W,
                       const float* __restrict__ dinv, float* __restrict__ H, int M){
  constexpr int LPR = NC/4;          // lanes per row
  constexpr int RPB = THREADS/LPR;   // rows per block
  __shared__ float As[RPB*K];
  const int row0 = blockIdx.x * RPB;
  const float4* A4 = (const float4*)(A + (size_t)row0*K);
  float4* As4 = (float4*)As;
  #pragma unroll
  for(int i = threadIdx.x; i < RPB*K/4; i += THREADS){
    float4 v = A4[i];
    if(RELU){
      v.x=fmaxf(v.x,0.f); v.y=fmaxf(v.y,0.f);
      v.z=fmaxf(v.z,0.f); v.w=fmaxf(v.w,0.f);
    }
    As4[i] = v;
  }
  __syncthreads();
  const int r  = threadIdx.x / LPR;
  const int cg = threadIdx.x % LPR;
  const float* a = As + r*K;
  const float4* W4 = (const float4*)W;
  float4 acc = make_float4(0.f,0.f,0.f,0.f);
  #pragma unroll 8
  for(int k=0;k<K;k++){
    float av = a[k];
    float4 w = W4[k*LPR + cg];
    acc.x = fmaf(av, w.x, acc.x);
    acc.y = fmaf(av, w.y, acc.y);
    acc.z = fmaf(av, w.z, acc.z);
    acc.w = fmaf(av, w.w, acc.w);
  }
  if(SCALE){
    float dv = dinv[row0 + r];
    acc.x*=dv; acc.y*=dv; acc.z*=dv; acc.w*=dv;
  }
  ((float4*)H)[(size_t)(row0 + r)*LPR + cg] = acc;
}

// one 64-lane wave per node: out[d,:] = dinv[d]*( g[d,:] + sum_{s in N(d)} g[s,:] ) + b
// where g[x,:] = h[x,:]*dinv[x] (pre-scaled in GEMM epilogue)
template<int NC>
__global__ void k_gather(const int* __restrict__ off, const int* __restrict__ ssrc,
                         const float* __restrict__ g, const float* __restrict__ dinv,
                         const float* __restrict__ bias, float* __restrict__ out, int M){
  const int w    = (blockIdx.x * blockDim.x + threadIdx.x) >> 6;
  const int lane = threadIdx.x & 63;
  if(w >= M) return;
  const int e0 = off[w], e1 = off[w+1];
  if(NC == 128){
    const float2* g2 = (const float2*)g;
    float2 acc = g2[(size_t)w*64 + lane];          // self-loop term
    int i = e0;
    for(; i+1 < e1; i += 2){
      int s0 = ssrc[i], s1 = ssrc[i+1];
      float2 v0 = g2[(size_t)s0*64 + lane];
      float2 v1 = g2[(size_t)s1*64 + lane];
      acc.x += v0.x + v1.x; acc.y += v0.y + v1.y;
    }
    if(i < e1){
      int s = ssrc[i];
      float2 v = g2[(size_t)s*64 + lane];
      acc.x += v.x; acc.y += v.y;
    }
    const float dd = dinv[w];
    float2 bb = ((const float2*)bias)[lane];
    float2 o;
    o.x = fmaf(acc.x, dd, bb.x);
    o.y = fmaf(acc.y, dd, bb.y);
    ((float2*)out)[(size_t)w*64 + lane] = o;
  } else { // NC == 64
    float acc = g[(size_t)w*NC + lane];
    int i = e0;
    for(; i+1 < e1; i += 2){
      int s0 = ssrc[i], s1 = ssrc[i+1];
      acc += g[(size_t)s0*NC + lane] + g[(size_t)s1*NC + lane];
    }
    if(i < e1) acc += g[(size_t)ssrc[i]*NC + lane];
    out[(size_t)w*NC + lane] = fmaf(acc, dinv[w], bias[lane]);
  }
}

extern "C" void kernel_launch(void* const* d_in, const int* in_sizes, int n_in,
                              void* d_out, int out_size, void* d_ws, size_t ws_size,
                              hipStream_t stream){
  const float* feat = (const float*)d_in[0];
  const int*   ei   = (const int*)d_in[1];
  const float* W1   = (const float*)d_in[2];
  const float* b1   = (const float*)d_in[3];
  const float* W2   = (const float*)d_in[4];
  const float* b2   = (const float*)d_in[5];
  float* out = (float*)d_out;

  const int M = in_sizes[0] / 256;   // 50000 nodes
  const int E = in_sizes[1] / 2;     // 800000 edges

  float* ws = (float*)d_ws;
  unsigned* cnt  = (unsigned*)ws;             // [0, 50176)
  float*    dinv = ws + 50176;                // [50176, 100352)
  int*      off  = (int*)(ws + 100352);       // 50001 ints
  int*      curs = (int*)(ws + 150656);       // 50176 ints
  int*      ssrc = (int*)(ws + 200832);       // 800000 ints
  float*    h1   = ws + 1000832;              // M*128
  float*    out1 = h1 + (size_t)M*128;        // M*128
  float*    h2   = h1;                        // reuse (dead after gather1)

  const int nbN = (M + THREADS-1)/THREADS;
  const int nbE = (E + THREADS-1)/THREADS;

  // CSR build (dst-sorted)
  k_zero_cnt<<<nbN, THREADS, 0, stream>>>(cnt, M);
  k_count<<<nbE, THREADS, 0, stream>>>(ei + E, cnt, E);
  k_scan<<<1, 1024, 0, stream>>>(cnt, off, M);
  k_node_init<<<nbN, THREADS, 0, stream>>>(cnt, off, dinv, curs, M);
  k_build<<<nbE, THREADS, 0, stream>>>(ei, curs, ssrc, E);

  const int gatherBlocks = (M*64 + THREADS-1)/THREADS;

  // ----- layer 1: 256 -> 128 -----
  k_gemm<256,128,false,true><<<M/8, THREADS, 0, stream>>>(feat, W1, dinv, h1, M);
  k_gather<128><<<gatherBlocks, THREADS, 0, stream>>>(off, ssrc, h1, dinv, b1, out1, M);

  // ----- layer 2: 128 -> 64 (relu fused into A load) -----
  k_gemm<128,64,true,true><<<M/16, THREADS, 0, stream>>>(out1, W2, dinv, h2, M);
  k_gather<64><<<gatherBlocks, THREADS, 0, stream>>>(off, ssrc, h2, dinv, b2, out, M);
}

// Round 3
// 400.229 us; speedup vs baseline: 5.7956x; 1.3461x over previous
//
#include <hip/hip_runtime.h>

#define THREADS 256

__global__ void k_zero_cnt(unsigned* __restrict__ cnt, int n){
  int i = blockIdx.x*blockDim.x + threadIdx.x;
  if(i < n) cnt[i] = 0u;
}

__global__ void k_count(const int* __restrict__ dst, unsigned* __restrict__ cnt, int E){
  int e = blockIdx.x*blockDim.x + threadIdx.x;
  if(e < E) atomicAdd(&cnt[dst[e]], 1u);
}

// single-block exclusive scan over cnt[0..M) -> off[0..M], off[M]=E
__global__ void k_scan(const unsigned* __restrict__ cnt, int* __restrict__ off, int M){
  __shared__ int part[1024];
  const int t = threadIdx.x;
  const int C = (M + 1023)/1024;
  const int base = t*C;
  int s = 0;
  for(int i=0;i<C;i++){ int idx=base+i; if(idx<M) s += (int)cnt[idx]; }
  part[t] = s;
  __syncthreads();
  for(int ofs=1; ofs<1024; ofs<<=1){
    int v = (t>=ofs)? part[t-ofs] : 0;
    __syncthreads();
    part[t] += v;
    __syncthreads();
  }
  int run = (t==0)? 0 : part[t-1];
  for(int i=0;i<C;i++){
    int idx=base+i;
    if(idx<M){ off[idx]=run; run += (int)cnt[idx]; }
  }
  if(t==1023) off[M] = part[1023];
}

__global__ void k_node_init(const unsigned* __restrict__ cnt, const int* __restrict__ off,
                            float* __restrict__ dinv, int* __restrict__ cursor, int M){
  int i = blockIdx.x*blockDim.x + threadIdx.x;
  if(i < M){
    dinv[i] = rsqrtf((float)(cnt[i] + 1u));  // +1 self-loop
    cursor[i] = off[i];
  }
}

__global__ void k_build(const int* __restrict__ ei, int* __restrict__ cursor,
                        int* __restrict__ ssrc, int E){
  int e = blockIdx.x*blockDim.x + threadIdx.x;
  if(e < E){
    int s = ei[e], d = ei[E+e];
    int p = atomicAdd(&cursor[d], 1);
    ssrc[p] = s;
  }
}

// Register-tiled GEMM: H[M,NC] = (relu?)(A[M,K]) @ W[K,NC], optional per-row dinv scale.
// BM=64, BK=16, 256 threads, thread tile TM=4 x TN (8 or 4).
// As stored transposed [BK][BM+4] so a thread's 4 rows load as one ds_read_b128.
template<int K, int NC, int TN, bool RELU, bool SCALE>
__global__ void k_gemm_rt(const float* __restrict__ A, const float* __restrict__ W,
                          const float* __restrict__ dinv, float* __restrict__ H, int M){
  constexpr int BM = 64, BK = 16, TM = 4;
  constexpr int BQ = NC/4;           // float4s per W row
  __shared__ float As[BK][BM+4];
  __shared__ float Bs[BK][NC];
  const int tid  = threadIdx.x;
  const int tx   = tid & 15;         // col group: cols tx*TN .. tx*TN+TN-1
  const int ty   = tid >> 4;         // row group: rows ty*4 .. ty*4+3
  const int row0 = blockIdx.x * BM;

  // A-load decomposition: thread -> (row r, k-quad q)
  const int ar = tid >> 2;           // 0..63
  const int aq = tid & 3;            // 0..3
  const int agr = min(row0 + ar, M-1);

  float acc[TM][TN];
  #pragma unroll
  for(int i=0;i<TM;i++)
    #pragma unroll
    for(int j=0;j<TN;j++) acc[i][j] = 0.f;

  for(int k0 = 0; k0 < K; k0 += BK){
    // load to regs
    float4 av = *(const float4*)(A + (size_t)agr*K + k0 + aq*4);
    if(RELU){
      av.x=fmaxf(av.x,0.f); av.y=fmaxf(av.y,0.f);
      av.z=fmaxf(av.z,0.f); av.w=fmaxf(av.w,0.f);
    }
    float4 bv[2];
    #pragma unroll
    for(int t=0; t<BK*BQ/256; t++){
      int f = tid + t*256;
      bv[t] = *(const float4*)(W + (size_t)(k0 + f/BQ)*NC + (f%BQ)*4);
    }
    __syncthreads();   // previous tile's reads complete before overwrite
    As[aq*4+0][ar] = av.x;
    As[aq*4+1][ar] = av.y;
    As[aq*4+2][ar] = av.z;
    As[aq*4+3][ar] = av.w;
    #pragma unroll
    for(int t=0; t<BK*BQ/256; t++){
      int f = tid + t*256;
      *(float4*)&Bs[f/BQ][(f%BQ)*4] = bv[t];
    }
    __syncthreads();
    #pragma unroll
    for(int kk=0; kk<BK; kk++){
      float4 a = *(const float4*)&As[kk][ty*TM];
      float b[TN];
      #pragma unroll
      for(int jq=0; jq<TN/4; jq++){
        float4 bb = *(const float4*)&Bs[kk][tx*TN + jq*4];
        b[jq*4+0]=bb.x; b[jq*4+1]=bb.y; b[jq*4+2]=bb.z; b[jq*4+3]=bb.w;
      }
      const float aa[4] = {a.x,a.y,a.z,a.w};
      #pragma unroll
      for(int i=0;i<TM;i++)
        #pragma unroll
        for(int j=0;j<TN;j++)
          acc[i][j] = fmaf(aa[i], b[j], acc[i][j]);
    }
  }

  #pragma unroll
  for(int i=0;i<TM;i++){
    int grow = row0 + ty*TM + i;
    if(grow >= M) break;
    float dv = SCALE ? dinv[grow] : 1.f;
    #pragma unroll
    for(int jq=0; jq<TN/4; jq++){
      float4 o;
      o.x = acc[i][jq*4+0]*dv; o.y = acc[i][jq*4+1]*dv;
      o.z = acc[i][jq*4+2]*dv; o.w = acc[i][jq*4+3]*dv;
      *(float4*)(H + (size_t)grow*NC + tx*TN + jq*4) = o;
    }
  }
}

// one 64-lane wave per node: out[d,:] = dinv[d]*( g[d,:] + sum_{s in N(d)} g[s,:] ) + b
// where g[x,:] = h[x,:]*dinv[x] (pre-scaled in GEMM epilogue)
template<int NC>
__global__ void k_gather(const int* __restrict__ off, const int* __restrict__ ssrc,
                         const float* __restrict__ g, const float* __restrict__ dinv,
                         const float* __restrict__ bias, float* __restrict__ out, int M){
  const int w    = (blockIdx.x * blockDim.x + threadIdx.x) >> 6;
  const int lane = threadIdx.x & 63;
  if(w >= M) return;
  const int e0 = off[w], e1 = off[w+1];
  if(NC == 128){
    const float2* g2 = (const float2*)g;
    float2 acc = g2[(size_t)w*64 + lane];          // self-loop term
    int i = e0;
    for(; i+1 < e1; i += 2){
      int s0 = ssrc[i], s1 = ssrc[i+1];
      float2 v0 = g2[(size_t)s0*64 + lane];
      float2 v1 = g2[(size_t)s1*64 + lane];
      acc.x += v0.x + v1.x; acc.y += v0.y + v1.y;
    }
    if(i < e1){
      int s = ssrc[i];
      float2 v = g2[(size_t)s*64 + lane];
      acc.x += v.x; acc.y += v.y;
    }
    const float dd = dinv[w];
    float2 bb = ((const float2*)bias)[lane];
    float2 o;
    o.x = fmaf(acc.x, dd, bb.x);
    o.y = fmaf(acc.y, dd, bb.y);
    ((float2*)out)[(size_t)w*64 + lane] = o;
  } else { // NC == 64
    float acc = g[(size_t)w*NC + lane];
    int i = e0;
    for(; i+1 < e1; i += 2){
      int s0 = ssrc[i], s1 = ssrc[i+1];
      acc += g[(size_t)s0*NC + lane] + g[(size_t)s1*NC + lane];
    }
    if(i < e1) acc += g[(size_t)ssrc[i]*NC + lane];
    out[(size_t)w*NC + lane] = fmaf(acc, dinv[w], bias[lane]);
  }
}

extern "C" void kernel_launch(void* const* d_in, const int* in_sizes, int n_in,
                              void* d_out, int out_size, void* d_ws, size_t ws_size,
                              hipStream_t stream){
  const float* feat = (const float*)d_in[0];
  const int*   ei   = (const int*)d_in[1];
  const float* W1   = (const float*)d_in[2];
  const float* b1   = (const float*)d_in[3];
  const float* W2   = (const float*)d_in[4];
  const float* b2   = (const float*)d_in[5];
  float* out = (float*)d_out;

  const int M = in_sizes[0] / 256;   // 50000 nodes
  const int E = in_sizes[1] / 2;     // 800000 edges

  float* ws = (float*)d_ws;
  unsigned* cnt  = (unsigned*)ws;             // [0, 50176)
  float*    dinv = ws + 50176;                // [50176, 100352)
  int*      off  = (int*)(ws + 100352);       // 50001 ints
  int*      curs = (int*)(ws + 150656);       // 50176 ints
  int*      ssrc = (int*)(ws + 200832);       // 800000 ints
  float*    h1   = ws + 1000832;              // M*128
  float*    out1 = h1 + (size_t)M*128;        // M*128
  float*    h2   = h1;                        // reuse (dead after gather1)

  const int nbN = (M + THREADS-1)/THREADS;
  const int nbE = (E + THREADS-1)/THREADS;

  // CSR build (dst-sorted)
  k_zero_cnt<<<nbN, THREADS, 0, stream>>>(cnt, M);
  k_count<<<nbE, THREADS, 0, stream>>>(ei + E, cnt, E);
  k_scan<<<1, 1024, 0, stream>>>(cnt, off, M);
  k_node_init<<<nbN, THREADS, 0, stream>>>(cnt, off, dinv, curs, M);
  k_build<<<nbE, THREADS, 0, stream>>>(ei, curs, ssrc, E);

  const int gatherBlocks = (M*64 + THREADS-1)/THREADS;
  const int gemmBlocks   = (M + 63)/64;

  // ----- layer 1: 256 -> 128 -----
  k_gemm_rt<256,128,8,false,true><<<gemmBlocks, THREADS, 0, stream>>>(feat, W1, dinv, h1, M);
  k_gather<128><<<gatherBlocks, THREADS, 0, stream>>>(off, ssrc, h1, dinv, b1, out1, M);

  // ----- layer 2: 128 -> 64 (relu fused into A load) -----
  k_gemm_rt<128,64,4,true,true><<<gemmBlocks, THREADS, 0, stream>>>(out1, W2, dinv, h2, M);
  k_gather<64><<<gatherBlocks, THREADS, 0, stream>>>(off, ssrc, h2, dinv, b2, out, M);
}

// Round 4
// 315.945 us; speedup vs baseline: 7.3417x; 1.2668x over previous
//
#include <hip/hip_runtime.h>

#define THREADS 256

__global__ void k_zero_cnt(unsigned* __restrict__ cnt, int n){
  int i = blockIdx.x*blockDim.x + threadIdx.x;
  if(i < n) cnt[i] = 0u;
}

__global__ void k_count(const int* __restrict__ dst, unsigned* __restrict__ cnt, int E){
  int e = blockIdx.x*blockDim.x + threadIdx.x;
  if(e < E) atomicAdd(&cnt[dst[e]], 1u);
}

// ---- hierarchical exclusive scan over cnt[0..M) ----
// pass 1: 256 threads/block, 1024 elems/block: local exclusive scan + block sum
__global__ void k_scan_local(const unsigned* __restrict__ cnt, int* __restrict__ off,
                             int* __restrict__ partials, int M){
  __shared__ int ts[256];
  const int t = threadIdx.x;
  const int base = blockIdx.x*1024 + t*4;
  int4 v = make_int4(0,0,0,0);
  if(base+3 < M) v = *(const int4*)(cnt+base);
  else {
    if(base+0<M) v.x=(int)cnt[base+0];
    if(base+1<M) v.y=(int)cnt[base+1];
    if(base+2<M) v.z=(int)cnt[base+2];
  }
  ts[t] = v.x+v.y+v.z+v.w;
  __syncthreads();
  for(int o=1;o<256;o<<=1){
    int u = (t>=o)? ts[t-o] : 0;
    __syncthreads();
    ts[t] += u;
    __syncthreads();
  }
  int ex = (t==0)? 0 : ts[t-1];
  if(base+0<M) off[base+0] = ex;
  if(base+1<M) off[base+1] = ex + v.x;
  if(base+2<M) off[base+2] = ex + v.x + v.y;
  if(base+3<M) off[base+3] = ex + v.x + v.y + v.z;
  if(t==255) partials[blockIdx.x] = ts[255];
}

// pass 2: single wave scans the <=64 block partials -> exclusive
__global__ void k_scan_part(int* __restrict__ partials, int NB){
  const int t = threadIdx.x;   // 64 threads
  int v = (t<NB)? partials[t] : 0;
  int s = v;
  for(int o=1;o<64;o<<=1){
    int u = __shfl_up(s, o);
    if(t >= o) s += u;
  }
  if(t<NB) partials[t] = s - v;
}

// pass 3: add block offsets; fuse node_init (dinv + cursor); off[M]=E
__global__ void k_scan_add(const unsigned* __restrict__ cnt, int* __restrict__ off,
                           const int* __restrict__ partials, float* __restrict__ dinv,
                           int* __restrict__ cursor, int M, int E){
  int i = blockIdx.x*blockDim.x + threadIdx.x;
  if(i < M){
    int o = off[i] + partials[i>>10];
    off[i] = o;
    cursor[i] = o;
    dinv[i] = rsqrtf((float)(cnt[i] + 1u));  // +1 self-loop
  }
  if(i == 0) off[M] = E;
}

__global__ void k_build(const int* __restrict__ ei, int* __restrict__ cursor,
                        int* __restrict__ ssrc, int E){
  int e = blockIdx.x*blockDim.x + threadIdx.x;
  if(e < E){
    int s = ei[e], d = ei[E+e];
    int p = atomicAdd(&cursor[d], 1);
    ssrc[p] = s;
  }
}

// Register-tiled GEMM: H[M,NC] = (relu?)(A[M,K]) @ W[K,NC], optional per-row dinv scale.
template<int K, int NC, int TN, bool RELU, bool SCALE>
__global__ void k_gemm_rt(const float* __restrict__ A, const float* __restrict__ W,
                          const float* __restrict__ dinv, float* __restrict__ H, int M){
  constexpr int BM = 64, BK = 16, TM = 4;
  constexpr int BQ = NC/4;           // float4s per W row
  __shared__ float As[BK][BM+4];
  __shared__ float Bs[BK][NC];
  const int tid  = threadIdx.x;
  const int tx   = tid & 15;
  const int ty   = tid >> 4;
  const int row0 = blockIdx.x * BM;

  const int ar = tid >> 2;
  const int aq = tid & 3;
  const int agr = min(row0 + ar, M-1);

  float acc[TM][TN];
  #pragma unroll
  for(int i=0;i<TM;i++)
    #pragma unroll
    for(int j=0;j<TN;j++) acc[i][j] = 0.f;

  for(int k0 = 0; k0 < K; k0 += BK){
    float4 av = *(const float4*)(A + (size_t)agr*K + k0 + aq*4);
    if(RELU){
      av.x=fmaxf(av.x,0.f); av.y=fmaxf(av.y,0.f);
      av.z=fmaxf(av.z,0.f); av.w=fmaxf(av.w,0.f);
    }
    float4 bv[2];
    #pragma unroll
    for(int t=0; t<BK*BQ/256; t++){
      int f = tid + t*256;
      bv[t] = *(const float4*)(W + (size_t)(k0 + f/BQ)*NC + (f%BQ)*4);
    }
    __syncthreads();
    As[aq*4+0][ar] = av.x;
    As[aq*4+1][ar] = av.y;
    As[aq*4+2][ar] = av.z;
    As[aq*4+3][ar] = av.w;
    #pragma unroll
    for(int t=0; t<BK*BQ/256; t++){
      int f = tid + t*256;
      *(float4*)&Bs[f/BQ][(f%BQ)*4] = bv[t];
    }
    __syncthreads();
    #pragma unroll
    for(int kk=0; kk<BK; kk++){
      float4 a = *(const float4*)&As[kk][ty*TM];
      float b[TN];
      #pragma unroll
      for(int jq=0; jq<TN/4; jq++){
        float4 bb = *(const float4*)&Bs[kk][tx*TN + jq*4];
        b[jq*4+0]=bb.x; b[jq*4+1]=bb.y; b[jq*4+2]=bb.z; b[jq*4+3]=bb.w;
      }
      const float aa[4] = {a.x,a.y,a.z,a.w};
      #pragma unroll
      for(int i=0;i<TM;i++)
        #pragma unroll
        for(int j=0;j<TN;j++)
          acc[i][j] = fmaf(aa[i], b[j], acc[i][j]);
    }
  }

  #pragma unroll
  for(int i=0;i<TM;i++){
    int grow = row0 + ty*TM + i;
    if(grow >= M) break;
    float dv = SCALE ? dinv[grow] : 1.f;
    #pragma unroll
    for(int jq=0; jq<TN/4; jq++){
      float4 o;
      o.x = acc[i][jq*4+0]*dv; o.y = acc[i][jq*4+1]*dv;
      o.z = acc[i][jq*4+2]*dv; o.w = acc[i][jq*4+3]*dv;
      *(float4*)(H + (size_t)grow*NC + tx*TN + jq*4) = o;
    }
  }
}

// one 64-lane wave per node: out[d,:] = dinv[d]*( g[d,:] + sum_{s in N(d)} g[s,:] ) + b
template<int NC>
__global__ void k_gather(const int* __restrict__ off, const int* __restrict__ ssrc,
                         const float* __restrict__ g, const float* __restrict__ dinv,
                         const float* __restrict__ bias, float* __restrict__ out, int M){
  const int w    = (blockIdx.x * blockDim.x + threadIdx.x) >> 6;
  const int lane = threadIdx.x & 63;
  if(w >= M) return;
  const int e0 = off[w], e1 = off[w+1];
  if(NC == 128){
    const float2* g2 = (const float2*)g;
    float2 acc = g2[(size_t)w*64 + lane];          // self-loop term
    int i = e0;
    for(; i+1 < e1; i += 2){
      int s0 = ssrc[i], s1 = ssrc[i+1];
      float2 v0 = g2[(size_t)s0*64 + lane];
      float2 v1 = g2[(size_t)s1*64 + lane];
      acc.x += v0.x + v1.x; acc.y += v0.y + v1.y;
    }
    if(i < e1){
      int s = ssrc[i];
      float2 v = g2[(size_t)s*64 + lane];
      acc.x += v.x; acc.y += v.y;
    }
    const float dd = dinv[w];
    float2 bb = ((const float2*)bias)[lane];
    float2 o;
    o.x = fmaf(acc.x, dd, bb.x);
    o.y = fmaf(acc.y, dd, bb.y);
    ((float2*)out)[(size_t)w*64 + lane] = o;
  } else { // NC == 64
    float acc = g[(size_t)w*NC + lane];
    int i = e0;
    for(; i+1 < e1; i += 2){
      int s0 = ssrc[i], s1 = ssrc[i+1];
      acc += g[(size_t)s0*NC + lane] + g[(size_t)s1*NC + lane];
    }
    if(i < e1) acc += g[(size_t)ssrc[i]*NC + lane];
    out[(size_t)w*NC + lane] = fmaf(acc, dinv[w], bias[lane]);
  }
}

extern "C" void kernel_launch(void* const* d_in, const int* in_sizes, int n_in,
                              void* d_out, int out_size, void* d_ws, size_t ws_size,
                              hipStream_t stream){
  const float* feat = (const float*)d_in[0];
  const int*   ei   = (const int*)d_in[1];
  const float* W1   = (const float*)d_in[2];
  const float* b1   = (const float*)d_in[3];
  const float* W2   = (const float*)d_in[4];
  const float* b2   = (const float*)d_in[5];
  float* out = (float*)d_out;

  const int M = in_sizes[0] / 256;   // 50000 nodes
  const int E = in_sizes[1] / 2;     // 800000 edges

  float* ws = (float*)d_ws;
  unsigned* cnt  = (unsigned*)ws;             // [0, 50176)
  float*    dinv = ws + 50176;                // [50176, 100352)
  int*      off  = (int*)(ws + 100352);       // 50001 ints
  int*      curs = (int*)(ws + 150656);       // 50176 ints
  int*      part = (int*)(ws + 200832);       // 64 ints
  int*      ssrc = (int*)(ws + 200960);       // 800000 ints
  float*    h1   = ws + 1000960;              // M*128
  float*    out1 = h1 + (size_t)M*128;        // M*128
  float*    h2   = h1;                        // reuse (dead after gather1)

  const int nbN = (M + THREADS-1)/THREADS;
  const int nbE = (E + THREADS-1)/THREADS;
  const int nbScan = (M + 1023)/1024;         // 49

  // CSR build (dst-sorted)
  k_zero_cnt<<<nbN, THREADS, 0, stream>>>(cnt, M);
  k_count<<<nbE, THREADS, 0, stream>>>(ei + E, cnt, E);
  k_scan_local<<<nbScan, 256, 0, stream>>>(cnt, off, part, M);
  k_scan_part<<<1, 64, 0, stream>>>(part, nbScan);
  k_scan_add<<<nbN, THREADS, 0, stream>>>(cnt, off, part, dinv, curs, M, E);
  k_build<<<nbE, THREADS, 0, stream>>>(ei, curs, ssrc, E);

  const int gatherBlocks = (M*64 + THREADS-1)/THREADS;
  const int gemmBlocks   = (M + 63)/64;

  // ----- layer 1: 256 -> 128 -----
  k_gemm_rt<256,128,8,false,true><<<gemmBlocks, THREADS, 0, stream>>>(feat, W1, dinv, h1, M);
  k_gather<128><<<gatherBlocks, THREADS, 0, stream>>>(off, ssrc, h1, dinv, b1, out1, M);

  // ----- layer 2: 128 -> 64 (relu fused into A load) -----
  k_gemm_rt<128,64,4,true,true><<<gemmBlocks, THREADS, 0, stream>>>(out1, W2, dinv, h2, M);
  k_gather<64><<<gatherBlocks, THREADS, 0, stream>>>(off, ssrc, h2, dinv, b2, out, M);
}

// Round 5
// 303.499 us; speedup vs baseline: 7.6428x; 1.0410x over previous
//
#include <hip/hip_runtime.h>

#define THREADS 256

__global__ void k_zero_cnt(unsigned* __restrict__ cnt, int n){
  int i = blockIdx.x*blockDim.x + threadIdx.x;
  if(i < n) cnt[i] = 0u;
}

__global__ void k_count(const int* __restrict__ dst, unsigned* __restrict__ cnt, int E){
  int e = blockIdx.x*blockDim.x + threadIdx.x;
  if(e < E) atomicAdd(&cnt[dst[e]], 1u);
}

// ---- hierarchical exclusive scan over cnt[0..M) ----
__global__ void k_scan_local(const unsigned* __restrict__ cnt, int* __restrict__ off,
                             int* __restrict__ partials, int M){
  __shared__ int ts[256];
  const int t = threadIdx.x;
  const int base = blockIdx.x*1024 + t*4;
  int4 v = make_int4(0,0,0,0);
  if(base+3 < M) v = *(const int4*)(cnt+base);
  else {
    if(base+0<M) v.x=(int)cnt[base+0];
    if(base+1<M) v.y=(int)cnt[base+1];
    if(base+2<M) v.z=(int)cnt[base+2];
  }
  ts[t] = v.x+v.y+v.z+v.w;
  __syncthreads();
  for(int o=1;o<256;o<<=1){
    int u = (t>=o)? ts[t-o] : 0;
    __syncthreads();
    ts[t] += u;
    __syncthreads();
  }
  int ex = (t==0)? 0 : ts[t-1];
  if(base+0<M) off[base+0] = ex;
  if(base+1<M) off[base+1] = ex + v.x;
  if(base+2<M) off[base+2] = ex + v.x + v.y;
  if(base+3<M) off[base+3] = ex + v.x + v.y + v.z;
  if(t==255) partials[blockIdx.x] = ts[255];
}

__global__ void k_scan_part(int* __restrict__ partials, int NB){
  const int t = threadIdx.x;   // 64 threads
  int v = (t<NB)? partials[t] : 0;
  int s = v;
  for(int o=1;o<64;o<<=1){
    int u = __shfl_up(s, o);
    if(t >= o) s += u;
  }
  if(t<NB) partials[t] = s - v;
}

__global__ void k_scan_add(const unsigned* __restrict__ cnt, int* __restrict__ off,
                           const int* __restrict__ partials, float* __restrict__ dinv,
                           int* __restrict__ cursor, int M, int E){
  int i = blockIdx.x*blockDim.x + threadIdx.x;
  if(i < M){
    int o = off[i] + partials[i>>10];
    off[i] = o;
    cursor[i] = o;
    dinv[i] = rsqrtf((float)(cnt[i] + 1u));  // +1 self-loop
  }
  if(i == 0) off[M] = E;
}

__global__ void k_build(const int* __restrict__ ei, int* __restrict__ cursor,
                        int* __restrict__ ssrc, int E){
  int e = blockIdx.x*blockDim.x + threadIdx.x;
  if(e < E){
    int s = ei[e], d = ei[E+e];
    int p = atomicAdd(&cursor[d], 1);
    ssrc[p] = s;
  }
}

// Register-tiled GEMM v2: H[M,NC] = (relu?)(A[M,K]) @ W[K,NC] (* dinv[row]).
// BM=128, BK=16, 256 threads. Thread tile TM x 8; the 8 cols are two float4s
// at tx*4 and NC/2+tx*4 (16B lane stride -> 2-way LDS aliasing only).
// As transposed [BK][BM+4]; Bs [BK][NC+4] (pad breaks mult-of-32 strides).
template<int K, int NC, int TM, bool RELU, bool SCALE>
__global__ void k_gemm_v2(const float* __restrict__ A, const float* __restrict__ W,
                          const float* __restrict__ dinv, float* __restrict__ H, int M){
  constexpr int BM = 128, BK = 16;
  constexpr int NTX = NC/8;            // tx groups (cols/thread = 8)
  __shared__ float As[BK][BM+4];
  __shared__ float Bs[BK][NC+4];
  const int tid  = threadIdx.x;
  const int tx   = tid % NTX;
  const int ty   = tid / NTX;          // ty*TM .. ty*TM+TM-1 rows
  const int row0 = blockIdx.x * BM;

  float acc[TM][8];
  #pragma unroll
  for(int i=0;i<TM;i++)
    #pragma unroll
    for(int j=0;j<8;j++) acc[i][j] = 0.f;

  for(int k0 = 0; k0 < K; k0 += BK){
    // stage A: BM*4 float4s, f -> (row=f>>2, q=f&3)
    float4 av[BM*4/THREADS];
    #pragma unroll
    for(int t=0; t<BM*4/THREADS; t++){
      int f = tid + t*THREADS;
      int r = min(row0 + (f>>2), M-1);
      float4 v = *(const float4*)(A + (size_t)r*K + k0 + (f&3)*4);
      if(RELU){
        v.x=fmaxf(v.x,0.f); v.y=fmaxf(v.y,0.f);
        v.z=fmaxf(v.z,0.f); v.w=fmaxf(v.w,0.f);
      }
      av[t] = v;
    }
    // stage B: BK*NC/4 float4s, f -> (brow=f/(NC/4), bc4=f%(NC/4))
    constexpr int BF4 = BK*NC/4/THREADS;  // 2 (NC=128) or 1 (NC=64)
    float4 bv[BF4];
    #pragma unroll
    for(int t=0; t<BF4; t++){
      int f = tid + t*THREADS;
      bv[t] = *(const float4*)(W + (size_t)(k0 + f/(NC/4))*NC + (f%(NC/4))*4);
    }
    __syncthreads();   // prev tile fully consumed
    #pragma unroll
    for(int t=0; t<BM*4/THREADS; t++){
      int f = tid + t*THREADS;
      int r = f>>2, q = f&3;
      As[q*4+0][r] = av[t].x;
      As[q*4+1][r] = av[t].y;
      As[q*4+2][r] = av[t].z;
      As[q*4+3][r] = av[t].w;
    }
    #pragma unroll
    for(int t=0; t<BF4; t++){
      int f = tid + t*THREADS;
      *(float4*)&Bs[f/(NC/4)][(f%(NC/4))*4] = bv[t];
    }
    __syncthreads();
    #pragma unroll
    for(int kk=0; kk<BK; kk++){
      float a[TM];
      #pragma unroll
      for(int i4=0; i4<TM/4; i4++){
        float4 aa = *(const float4*)&As[kk][ty*TM + i4*4];
        a[i4*4+0]=aa.x; a[i4*4+1]=aa.y; a[i4*4+2]=aa.z; a[i4*4+3]=aa.w;
      }
      float4 b0 = *(const float4*)&Bs[kk][tx*4];
      float4 b1 = *(const float4*)&Bs[kk][NC/2 + tx*4];
      const float b[8] = {b0.x,b0.y,b0.z,b0.w,b1.x,b1.y,b1.z,b1.w};
      #pragma unroll
      for(int i=0;i<TM;i++)
        #pragma unroll
        for(int j=0;j<8;j++)
          acc[i][j] = fmaf(a[i], b[j], acc[i][j]);
    }
  }

  #pragma unroll
  for(int i=0;i<TM;i++){
    int grow = row0 + ty*TM + i;
    if(grow < M){
      float dv = SCALE ? dinv[grow] : 1.f;
      float4 o0, o1;
      o0.x=acc[i][0]*dv; o0.y=acc[i][1]*dv; o0.z=acc[i][2]*dv; o0.w=acc[i][3]*dv;
      o1.x=acc[i][4]*dv; o1.y=acc[i][5]*dv; o1.z=acc[i][6]*dv; o1.w=acc[i][7]*dv;
      *(float4*)(H + (size_t)grow*NC + tx*4) = o0;
      *(float4*)(H + (size_t)grow*NC + NC/2 + tx*4) = o1;
    }
  }
}

// one 64-lane wave per node: out[d,:] = dinv[d]*( g[d,:] + sum_{s in N(d)} g[s,:] ) + b
template<int NC>
__global__ void k_gather(const int* __restrict__ off, const int* __restrict__ ssrc,
                         const float* __restrict__ g, const float* __restrict__ dinv,
                         const float* __restrict__ bias, float* __restrict__ out, int M){
  const int w    = (blockIdx.x * blockDim.x + threadIdx.x) >> 6;
  const int lane = threadIdx.x & 63;
  if(w >= M) return;
  const int e0 = off[w], e1 = off[w+1];
  if(NC == 128){
    const float2* g2 = (const float2*)g;
    float2 acc = g2[(size_t)w*64 + lane];          // self-loop term
    int i = e0;
    for(; i+1 < e1; i += 2){
      int s0 = ssrc[i], s1 = ssrc[i+1];
      float2 v0 = g2[(size_t)s0*64 + lane];
      float2 v1 = g2[(size_t)s1*64 + lane];
      acc.x += v0.x + v1.x; acc.y += v0.y + v1.y;
    }
    if(i < e1){
      int s = ssrc[i];
      float2 v = g2[(size_t)s*64 + lane];
      acc.x += v.x; acc.y += v.y;
    }
    const float dd = dinv[w];
    float2 bb = ((const float2*)bias)[lane];
    float2 o;
    o.x = fmaf(acc.x, dd, bb.x);
    o.y = fmaf(acc.y, dd, bb.y);
    ((float2*)out)[(size_t)w*64 + lane] = o;
  } else { // NC == 64
    float acc = g[(size_t)w*NC + lane];
    int i = e0;
    for(; i+1 < e1; i += 2){
      int s0 = ssrc[i], s1 = ssrc[i+1];
      acc += g[(size_t)s0*NC + lane] + g[(size_t)s1*NC + lane];
    }
    if(i < e1) acc += g[(size_t)ssrc[i]*NC + lane];
    out[(size_t)w*NC + lane] = fmaf(acc, dinv[w], bias[lane]);
  }
}

extern "C" void kernel_launch(void* const* d_in, const int* in_sizes, int n_in,
                              void* d_out, int out_size, void* d_ws, size_t ws_size,
                              hipStream_t stream){
  const float* feat = (const float*)d_in[0];
  const int*   ei   = (const int*)d_in[1];
  const float* W1   = (const float*)d_in[2];
  const float* b1   = (const float*)d_in[3];
  const float* W2   = (const float*)d_in[4];
  const float* b2   = (const float*)d_in[5];
  float* out = (float*)d_out;

  const int M = in_sizes[0] / 256;   // 50000 nodes
  const int E = in_sizes[1] / 2;     // 800000 edges

  float* ws = (float*)d_ws;
  unsigned* cnt  = (unsigned*)ws;             // [0, 50176)
  float*    dinv = ws + 50176;                // [50176, 100352)
  int*      off  = (int*)(ws + 100352);       // 50001 ints
  int*      curs = (int*)(ws + 150656);       // 50176 ints
  int*      part = (int*)(ws + 200832);       // 64 ints
  int*      ssrc = (int*)(ws + 200960);       // 800000 ints
  float*    h1   = ws + 1000960;              // M*128
  float*    out1 = h1 + (size_t)M*128;        // M*128
  float*    h2   = h1;                        // reuse (dead after gather1)

  const int nbN = (M + THREADS-1)/THREADS;
  const int nbE = (E + THREADS-1)/THREADS;
  const int nbScan = (M + 1023)/1024;         // 49

  // CSR build (dst-sorted)
  k_zero_cnt<<<nbN, THREADS, 0, stream>>>(cnt, M);
  k_count<<<nbE, THREADS, 0, stream>>>(ei + E, cnt, E);
  k_scan_local<<<nbScan, 256, 0, stream>>>(cnt, off, part, M);
  k_scan_part<<<1, 64, 0, stream>>>(part, nbScan);
  k_scan_add<<<nbN, THREADS, 0, stream>>>(cnt, off, part, dinv, curs, M, E);
  k_build<<<nbE, THREADS, 0, stream>>>(ei, curs, ssrc, E);

  const int gatherBlocks = (M*64 + THREADS-1)/THREADS;
  const int gemmBlocks   = (M + 127)/128;

  // ----- layer 1: 256 -> 128 -----
  k_gemm_v2<256,128,8,false,true><<<gemmBlocks, THREADS, 0, stream>>>(feat, W1, dinv, h1, M);
  k_gather<128><<<gatherBlocks, THREADS, 0, stream>>>(off, ssrc, h1, dinv, b1, out1, M);

  // ----- layer 2: 128 -> 64 (relu fused into A load) -----
  k_gemm_v2<128,64,4,true,true><<<gemmBlocks, THREADS, 0, stream>>>(out1, W2, dinv, h2, M);
  k_gather<64><<<gatherBlocks, THREADS, 0, stream>>>(off, ssrc, h2, dinv, b2, out, M);
}

// Round 6
// 255.383 us; speedup vs baseline: 9.0827x; 1.1884x over previous
//
#include <hip/hip_runtime.h>

#define THREADS 256

typedef _Float16 f16;
typedef f16   f16x8 __attribute__((ext_vector_type(8)));
typedef float f32x4 __attribute__((ext_vector_type(4)));

__global__ void k_zero_cnt(unsigned* __restrict__ cnt, int n){
  int i = blockIdx.x*blockDim.x + threadIdx.x;
  if(i < n) cnt[i] = 0u;
}

__global__ void k_count(const int* __restrict__ dst, unsigned* __restrict__ cnt, int E){
  int e = blockIdx.x*blockDim.x + threadIdx.x;
  if(e < E) atomicAdd(&cnt[dst[e]], 1u);
}

// ---- hierarchical exclusive scan over cnt[0..M) ----
__global__ void k_scan_local(const unsigned* __restrict__ cnt, int* __restrict__ off,
                             int* __restrict__ partials, int M){
  __shared__ int ts[256];
  const int t = threadIdx.x;
  const int base = blockIdx.x*1024 + t*4;
  int4 v = make_int4(0,0,0,0);
  if(base+3 < M) v = *(const int4*)(cnt+base);
  else {
    if(base+0<M) v.x=(int)cnt[base+0];
    if(base+1<M) v.y=(int)cnt[base+1];
    if(base+2<M) v.z=(int)cnt[base+2];
  }
  ts[t] = v.x+v.y+v.z+v.w;
  __syncthreads();
  for(int o=1;o<256;o<<=1){
    int u = (t>=o)? ts[t-o] : 0;
    __syncthreads();
    ts[t] += u;
    __syncthreads();
  }
  int ex = (t==0)? 0 : ts[t-1];
  if(base+0<M) off[base+0] = ex;
  if(base+1<M) off[base+1] = ex + v.x;
  if(base+2<M) off[base+2] = ex + v.x + v.y;
  if(base+3<M) off[base+3] = ex + v.x + v.y + v.z;
  if(t==255) partials[blockIdx.x] = ts[255];
}

__global__ void k_scan_part(int* __restrict__ partials, int NB){
  const int t = threadIdx.x;   // 64 threads
  int v = (t<NB)? partials[t] : 0;
  int s = v;
  for(int o=1;o<64;o<<=1){
    int u = __shfl_up(s, o);
    if(t >= o) s += u;
  }
  if(t<NB) partials[t] = s - v;
}

__global__ void k_scan_add(const unsigned* __restrict__ cnt, int* __restrict__ off,
                           const int* __restrict__ partials, float* __restrict__ dinv,
                           int* __restrict__ cursor, int M, int E){
  int i = blockIdx.x*blockDim.x + threadIdx.x;
  if(i < M){
    int o = off[i] + partials[i>>10];
    off[i] = o;
    cursor[i] = o;
    dinv[i] = rsqrtf((float)(cnt[i] + 1u));  // +1 self-loop
  }
  if(i == 0) off[M] = E;
}

__global__ void k_build(const int* __restrict__ ei, int* __restrict__ cursor,
                        int* __restrict__ ssrc, int E){
  int e = blockIdx.x*blockDim.x + threadIdx.x;
  if(e < E){
    int s = ei[e], d = ei[E+e];
    int p = atomicAdd(&cursor[d], 1);
    ssrc[p] = s;
  }
}

// ---- MFMA GEMM with f16x2 error-compensated split ----
// H[M,N] = (relu?)(A[M,K]) @ W[K,N] * dinv[row]
// a*b ~= ah*bh + ah*bl + al*bh  (al*bl ~2^-22 dropped), f32 accumulate.
// Block: 256 thr (4 waves, 2x2), BM=128, BN=N (128 or 64), BK=32.
// LDS: Ah/Al[row][k], Bh/Bl[col][k] (K-transposed), k-stride 40 halfs (pad).
template<int K, int N, bool RELU>
__global__ void k_gemm_mfma(const float* __restrict__ A, const float* __restrict__ W,
                            const float* __restrict__ dinv, float* __restrict__ H, int M){
  constexpr int BM = 128, BK = 32, BN = N;
  constexpr int AST = 40;                 // padded k stride (halfs)
  constexpr int NM = 4;                   // 64 rows per wave / 16
  constexpr int NN = BN/32;               // 4 (BN=128) or 2 (BN=64)
  constexpr int SKN = BK*BN/THREADS;      // B: k's per thread (16 or 8)
  __shared__ f16 Ah[BM*AST], Al[BM*AST], Bh[BN*AST], Bl[BN*AST];

  const int tid  = threadIdx.x;
  const int row0 = blockIdx.x*BM;
  const int wv = tid>>6, l = tid&63;
  const int wr = wv>>1, wc = wv&1;        // 2x2 wave grid
  const int lr = l&15, lk = l>>4;         // frag row(col), k-group

  // staging coords
  const int sar = tid>>1, sak = (tid&1)*16;           // A: 1 row, 16 k
  const long long garow = min(row0+sar, M-1);
  const int sc = tid % BN, sk0 = (tid/BN)*SKN;        // B: 1 col, SKN k

  f32x4 acc[NM][NN] = {};

  for(int k0 = 0; k0 < K; k0 += BK){
    // global loads to regs
    float avals[16];
    #pragma unroll
    for(int q=0;q<4;q++){
      float4 v = *(const float4*)(A + garow*K + k0 + sak + q*4);
      if(RELU){
        v.x=fmaxf(v.x,0.f); v.y=fmaxf(v.y,0.f);
        v.z=fmaxf(v.z,0.f); v.w=fmaxf(v.w,0.f);
      }
      avals[q*4+0]=v.x; avals[q*4+1]=v.y; avals[q*4+2]=v.z; avals[q*4+3]=v.w;
    }
    float bvals[SKN];
    #pragma unroll
    for(int i=0;i<SKN;i++) bvals[i] = W[(size_t)(k0+sk0+i)*N + sc];

    __syncthreads();   // previous tile fully consumed

    #pragma unroll
    for(int s=0;s<2;s++){
      f16x8 hi, lo;
      #pragma unroll
      for(int j=0;j<8;j++){
        float x = avals[s*8+j];
        f16 h = (f16)x;
        hi[j] = h; lo[j] = (f16)(x - (float)h);
      }
      *(f16x8*)&Ah[sar*AST + sak + s*8] = hi;
      *(f16x8*)&Al[sar*AST + sak + s*8] = lo;
    }
    #pragma unroll
    for(int s=0;s<SKN/8;s++){
      f16x8 hi, lo;
      #pragma unroll
      for(int j=0;j<8;j++){
        float x = bvals[s*8+j];
        f16 h = (f16)x;
        hi[j] = h; lo[j] = (f16)(x - (float)h);
      }
      *(f16x8*)&Bh[sc*AST + sk0 + s*8] = hi;
      *(f16x8*)&Bl[sc*AST + sk0 + s*8] = lo;
    }
    __syncthreads();

    // fragments + MFMA
    f16x8 afh[NM], afl[NM], bfh[NN], bfl[NN];
    #pragma unroll
    for(int m=0;m<NM;m++){
      int r = wr*64 + m*16 + lr;
      afh[m] = *(const f16x8*)&Ah[r*AST + lk*8];
      afl[m] = *(const f16x8*)&Al[r*AST + lk*8];
    }
    #pragma unroll
    for(int n=0;n<NN;n++){
      int c = wc*(BN/2) + n*16 + lr;
      bfh[n] = *(const f16x8*)&Bh[c*AST + lk*8];
      bfl[n] = *(const f16x8*)&Bl[c*AST + lk*8];
    }
    #pragma unroll
    for(int m=0;m<NM;m++)
      #pragma unroll
      for(int n=0;n<NN;n++){
        acc[m][n] = __builtin_amdgcn_mfma_f32_16x16x32_f16(afh[m], bfh[n], acc[m][n], 0,0,0);
        acc[m][n] = __builtin_amdgcn_mfma_f32_16x16x32_f16(afh[m], bfl[n], acc[m][n], 0,0,0);
        acc[m][n] = __builtin_amdgcn_mfma_f32_16x16x32_f16(afl[m], bfh[n], acc[m][n], 0,0,0);
      }
  }

  // epilogue: D row = lk*4+reg, col = lr
  #pragma unroll
  for(int m=0;m<NM;m++){
    int grb = row0 + wr*64 + m*16 + lk*4;
    #pragma unroll
    for(int reg=0;reg<4;reg++){
      int gr = grb + reg;
      if(gr < M){
        float dv = dinv[gr];
        #pragma unroll
        for(int n=0;n<NN;n++){
          int gc = wc*(BN/2) + n*16 + lr;
          H[(size_t)gr*N + gc] = acc[m][n][reg] * dv;
        }
      }
    }
  }
}

// one 64-lane wave per node: out[d,:] = dinv[d]*( g[d,:] + sum_{s in N(d)} g[s,:] ) + b
template<int NC>
__global__ void k_gather(const int* __restrict__ off, const int* __restrict__ ssrc,
                         const float* __restrict__ g, const float* __restrict__ dinv,
                         const float* __restrict__ bias, float* __restrict__ out, int M){
  const int w    = (blockIdx.x * blockDim.x + threadIdx.x) >> 6;
  const int lane = threadIdx.x & 63;
  if(w >= M) return;
  const int e0 = off[w], e1 = off[w+1];
  if(NC == 128){
    const float2* g2 = (const float2*)g;
    float2 acc = g2[(size_t)w*64 + lane];          // self-loop term
    int i = e0;
    for(; i+1 < e1; i += 2){
      int s0 = ssrc[i], s1 = ssrc[i+1];
      float2 v0 = g2[(size_t)s0*64 + lane];
      float2 v1 = g2[(size_t)s1*64 + lane];
      acc.x += v0.x + v1.x; acc.y += v0.y + v1.y;
    }
    if(i < e1){
      int s = ssrc[i];
      float2 v = g2[(size_t)s*64 + lane];
      acc.x += v.x; acc.y += v.y;
    }
    const float dd = dinv[w];
    float2 bb = ((const float2*)bias)[lane];
    float2 o;
    o.x = fmaf(acc.x, dd, bb.x);
    o.y = fmaf(acc.y, dd, bb.y);
    ((float2*)out)[(size_t)w*64 + lane] = o;
  } else { // NC == 64
    float acc = g[(size_t)w*NC + lane];
    int i = e0;
    for(; i+1 < e1; i += 2){
      int s0 = ssrc[i], s1 = ssrc[i+1];
      acc += g[(size_t)s0*NC + lane] + g[(size_t)s1*NC + lane];
    }
    if(i < e1) acc += g[(size_t)ssrc[i]*NC + lane];
    out[(size_t)w*NC + lane] = fmaf(acc, dinv[w], bias[lane]);
  }
}

extern "C" void kernel_launch(void* const* d_in, const int* in_sizes, int n_in,
                              void* d_out, int out_size, void* d_ws, size_t ws_size,
                              hipStream_t stream){
  const float* feat = (const float*)d_in[0];
  const int*   ei   = (const int*)d_in[1];
  const float* W1   = (const float*)d_in[2];
  const float* b1   = (const float*)d_in[3];
  const float* W2   = (const float*)d_in[4];
  const float* b2   = (const float*)d_in[5];
  float* out = (float*)d_out;

  const int M = in_sizes[0] / 256;   // 50000 nodes
  const int E = in_sizes[1] / 2;     // 800000 edges

  float* ws = (float*)d_ws;
  unsigned* cnt  = (unsigned*)ws;             // [0, 50176)
  float*    dinv = ws + 50176;                // [50176, 100352)
  int*      off  = (int*)(ws + 100352);       // 50001 ints
  int*      curs = (int*)(ws + 150656);       // 50176 ints
  int*      part = (int*)(ws + 200832);       // 64 ints
  int*      ssrc = (int*)(ws + 200960);       // 800000 ints
  float*    h1   = ws + 1000960;              // M*128
  float*    out1 = h1 + (size_t)M*128;        // M*128
  float*    h2   = h1;                        // reuse (dead after gather1)

  const int nbN = (M + THREADS-1)/THREADS;
  const int nbE = (E + THREADS-1)/THREADS;
  const int nbScan = (M + 1023)/1024;         // 49

  // CSR build (dst-sorted)
  k_zero_cnt<<<nbN, THREADS, 0, stream>>>(cnt, M);
  k_count<<<nbE, THREADS, 0, stream>>>(ei + E, cnt, E);
  k_scan_local<<<nbScan, 256, 0, stream>>>(cnt, off, part, M);
  k_scan_part<<<1, 64, 0, stream>>>(part, nbScan);
  k_scan_add<<<nbN, THREADS, 0, stream>>>(cnt, off, part, dinv, curs, M, E);
  k_build<<<nbE, THREADS, 0, stream>>>(ei, curs, ssrc, E);

  const int gatherBlocks = (M*64 + THREADS-1)/THREADS;
  const int gemmBlocks   = (M + 127)/128;

  // ----- layer 1: 256 -> 128 -----
  k_gemm_mfma<256,128,false><<<gemmBlocks, THREADS, 0, stream>>>(feat, W1, dinv, h1, M);
  k_gather<128><<<gatherBlocks, THREADS, 0, stream>>>(off, ssrc, h1, dinv, b1, out1, M);

  // ----- layer 2: 128 -> 64 (relu fused into A staging) -----
  k_gemm_mfma<128,64,true><<<gemmBlocks, THREADS, 0, stream>>>(out1, W2, dinv, h2, M);
  k_gather<64><<<gatherBlocks, THREADS, 0, stream>>>(off, ssrc, h2, dinv, b2, out, M);
}